// Round 22
// baseline (103.857 us; speedup 1.0000x reference)
//
#include <hip/hip_runtime.h>
#include <hip/hip_bf16.h>

#define NSEG 200
#define STRENGTH 1e-3f
#define NFB 16384                   // fine bins per segment
#define FSCALE (16384.0f / 12.0f)
#define BT 1024                     // threads per block
#define SPLIT 5                     // windows (partitions) per segment
#define QH 4                        // k_hist1 blocks per segment
#define WINCAP 9728                 // max window slots (n/5 + maxbin + slack)
#define EPT 10                      // max elements per thread
#define PSTRIDE (NFB + 8)           // u16 per segment in global pfx table
#define PCH 8192                    // elements per k_part chunk
#define SLICE_E 8200                // LDS pfx slice capacity (entries)

__device__ __forceinline__ int fbin_of(float v) {
    float t = (v + 6.0f) * FSCALE;
    int b = (int)floorf(t);
    return b < 0 ? 0 : (b > NFB - 1 ? NFB - 1 : b);
}

// ---- 1a. per-(segment,quarter): private packed-u16 hist -> global partials ----
// histp is aliased onto `part` (k_part writes part only after k_hist2 reads histp).
__global__ void __launch_bounds__(BT)
k_hist1(const float* __restrict__ x, const int* __restrict__ seg,
        int* __restrict__ seg_starts, float* __restrict__ segSums,
        unsigned* __restrict__ gcur, unsigned* __restrict__ histp, int N) {
    __shared__ unsigned hw[NFB / 2];    // 32 KB packed u16 counts
    __shared__ int sh2[2];
    int b = blockIdx.x;
    int s = b >> 2;
    int h = b & 3;
    int t = threadIdx.x;
    if (t <= 1) {
        int key = s + t;
        int lo = 0, hi = N;
        while (lo < hi) { int mid = (lo + hi) >> 1; if (seg[mid] < key) lo = mid + 1; else hi = mid; }
        sh2[t] = lo;
    }
    if (h == 0) {
        if (t < 8) gcur[s * 8 + t] = 0u;
        if (t == 2) segSums[s] = 0.f;
    }
    for (int k = t; k < NFB / 2; k += BT) hw[k] = 0;
    __syncthreads();
    int st = sh2[0], en = sh2[1];
    if (h == 0 && t == 3) { seg_starts[s] = st; if (s == NSEG - 1) seg_starts[NSEG] = N; }
    int n = en - st;
    // quarter range [a0, a1)
    int q0 = n >> 2;
    int a0 = st + h * q0;
    int a1 = (h == 3) ? en : (a0 + q0);
    int m = a1 - a0;
    const float* xs = x + a0;
    if (m > 0) {
        int head = min(m, (int)((4 - (a0 & 3)) & 3));
        for (int k = t; k < head; k += BT) { int f = fbin_of(xs[k]); atomicAdd(&hw[f >> 1], 1u << ((f & 1) * 16)); }
        int nv = (m - head) >> 2;
        const float4* xs4 = (const float4*)(xs + head);
        for (int j = t; j < nv; j += BT) {
            float4 v = xs4[j];
            int f0 = fbin_of(v.x), f1 = fbin_of(v.y), f2 = fbin_of(v.z), f3 = fbin_of(v.w);
            atomicAdd(&hw[f0 >> 1], 1u << ((f0 & 1) * 16));
            atomicAdd(&hw[f1 >> 1], 1u << ((f1 & 1) * 16));
            atomicAdd(&hw[f2 >> 1], 1u << ((f2 & 1) * 16));
            atomicAdd(&hw[f3 >> 1], 1u << ((f3 & 1) * 16));
        }
        for (int k = head + nv * 4 + t; k < m; k += BT) { int f = fbin_of(xs[k]); atomicAdd(&hw[f >> 1], 1u << ((f & 1) * 16)); }
    }
    __syncthreads();
    unsigned* hp = histp + (size_t)b * (NFB / 2);
    for (int k = t; k < NFB / 2; k += BT) hp[k] = hw[k];
}

// ---- 1b. per-segment: merge 4 partials -> prefix -> pfxg; quantile bounds ----
__global__ void __launch_bounds__(BT)
k_hist2(const unsigned* __restrict__ histp, unsigned short* __restrict__ pfxg,
        int* __restrict__ Bg, int* __restrict__ Bpos) {
    __shared__ unsigned hw[NFB / 2];    // 32 KB merged packed prefix (for quantile search)
    __shared__ unsigned wsum[16];
    __shared__ int sh2[1];
    int s = blockIdx.x;
    int t = threadIdx.x;
    const unsigned* h0 = histp + (size_t)(s * 4 + 0) * (NFB / 2);
    const unsigned* h1 = histp + (size_t)(s * 4 + 1) * (NFB / 2);
    const unsigned* h2 = histp + (size_t)(s * 4 + 2) * (NFB / 2);
    const unsigned* h3 = histp + (size_t)(s * 4 + 3) * (NFB / 2);
    // exclusive prefix over 16384 bins: thread owns 8 words (16 bins)
    unsigned wv[8]; unsigned run = 0;
    #pragma unroll
    for (int i = 0; i < 8; ++i) {
        int k = t * 8 + i;
        unsigned w = h0[k] + h1[k] + h2[k] + h3[k];   // field-wise add (sums <= n < 65536)
        unsigned c0 = w & 0xffffu, c1 = w >> 16;
        wv[i] = run | ((run + c0) << 16);
        run += c0 + c1;
    }
    unsigned incl = run;
    for (int off = 1; off < 64; off <<= 1) {
        unsigned nv2 = __shfl_up(incl, off, 64);
        if ((t & 63) >= off) incl += nv2;
    }
    if ((t & 63) == 63) wsum[t >> 6] = incl;
    __syncthreads();
    unsigned wb = 0; int myw = t >> 6;
    #pragma unroll
    for (int j = 0; j < 16; ++j) wb += (j < myw) ? wsum[j] : 0u;
    unsigned base = wb + incl - run;
    unsigned bb = base | (base << 16);
    unsigned short* pp = pfxg + (size_t)s * PSTRIDE;
    #pragma unroll
    for (int i = 0; i < 8; ++i) {
        unsigned pw = wv[i] + bb;
        hw[t * 8 + i] = pw;                       // keep packed prefix for quantile search
        ((unsigned*)pp)[t * 8 + i] = pw;          // global u16 prefix table
    }
    if (t == BT - 1) { pp[NFB] = (unsigned short)(base + run); sh2[0] = (int)(base + run); }
    __syncthreads();
    int nsh = sh2[0];
    if (t == 0) { Bg[s * 8 + 0] = 0; Bg[s * 8 + SPLIT] = NFB; Bpos[s * 8 + 0] = 0; Bpos[s * 8 + SPLIT] = nsh; }
    if (t >= 1 && t < SPLIT) {
        int target = (int)(((long)t * nsh) / SPLIT);
        int lo = 0, hi = NFB - 1;
        while (lo < hi) {
            int mid = (lo + hi) >> 1;
            int pv = (int)((hw[(mid + 1) >> 1] >> (((mid + 1) & 1) * 16)) & 0xffffu);
            if (pv > target) hi = mid; else lo = mid + 1;
        }
        Bg[s * 8 + t] = lo;
        Bpos[s * 8 + t] = (int)((hw[lo >> 1] >> ((lo & 1) * 16)) & 0xffffu);
    }
}

// ---- 2. single-pass 5-way partition scatter (block-aggregated, coalesced runs) ----
__global__ void __launch_bounds__(1024)
k_part(const float* __restrict__ x, const int* __restrict__ seg_starts,
       const int* __restrict__ Bg, const int* __restrict__ Bpos,
       unsigned* __restrict__ gcur, float* __restrict__ part, int N) {
    __shared__ int sst[NSEG + 1];
    __shared__ unsigned hh[16][12];
    __shared__ int gb[10];
    __shared__ int sB[8];
    int t = threadIdx.x;
    for (int k = t; k < NSEG + 1; k += 1024) sst[k] = seg_starts[k];
    if (t < 192) ((unsigned*)hh)[t] = 0u;
    __syncthreads();
    int base = blockIdx.x * PCH;
    if (base >= N) return;
    int lo = 0, hi = NSEG - 1;
    while (lo < hi) { int mid = (lo + hi) >> 1; if (base < sst[mid + 1]) hi = mid; else lo = mid + 1; }
    int s0 = lo, bnd = sst[s0 + 1];
    if (t < 4) sB[t] = Bg[s0 * 8 + 1 + t];
    else if (t < 8) sB[t] = (s0 + 1 < NSEG) ? Bg[(s0 + 1) * 8 + 1 + (t - 4)] : 0x7fffffff;
    __syncthreads();
    int grp = t >> 6;
    float vv[8]; unsigned pk[8];
    const float4* x4 = (const float4*)(x + base);
    #pragma unroll
    for (int it = 0; it < 2; ++it) {
        int j = it * 1024 + t;
        int gi = base + j * 4;
        float4 v4 = (gi + 3 < N) ? x4[j] : make_float4(0.f, 0.f, 0.f, 0.f);
        #pragma unroll
        for (int e = 0; e < 4; ++e) {
            int i = it * 4 + e;
            float v = (e == 0) ? v4.x : (e == 1) ? v4.y : (e == 2) ? v4.z : v4.w;
            vv[i] = v;
            int g = gi + e;
            if (g < N) {
                int off = (g >= bnd) ? 4 : 0;
                int f = fbin_of(v);
                int p = (f >= sB[off]) + (f >= sB[off + 1]) + (f >= sB[off + 2]) + (f >= sB[off + 3]);
                int sp = (off >> 2) * 5 + p;
                unsigned lr = atomicAdd(&hh[grp][sp], 1u);
                pk[i] = ((unsigned)sp << 10) | lr;
            } else pk[i] = 0xffffffffu;
        }
    }
    __syncthreads();
    if (t < 10) {
        unsigned run = 0;
        #pragma unroll
        for (int g = 0; g < 16; ++g) { unsigned c = hh[g][t]; hh[g][t] = run; run += c; }
        int s = s0 + (t >= 5);
        int p = (t >= 5) ? t - 5 : t;
        int rsv = 0;
        if (run > 0 && s < NSEG) rsv = (int)atomicAdd(&gcur[s * 8 + p], run);
        gb[t] = (s < NSEG) ? (sst[s] + Bpos[s * 8 + p] + rsv) : 0;
    }
    __syncthreads();
    #pragma unroll
    for (int i = 0; i < 8; ++i) {
        if (pk[i] == 0xffffffffu) continue;
        int sp = (int)(pk[i] >> 10);
        int lr = (int)(pk[i] & 1023u);
        part[gb[sp] + (int)hh[grp][sp] + lr] = vv[i];
    }
}

// ---- 3. per-(segment,window): slice-pfx stage -> rank -> in-place sort -> coalesced diff ----
// s = bid % NSEG keeps all 5 blocks of a segment on one XCD (NSEG % 8 == 0).
__global__ void __launch_bounds__(BT)
k_seg(const float* __restrict__ part, const float* __restrict__ y,
      const int* __restrict__ seg_starts, const unsigned short* __restrict__ pfxg,
      const int* __restrict__ Bg, float* __restrict__ segSums) {
    __shared__ unsigned short slice[SLICE_E];          // 16400 B: pfx[Fa..Fb]
    __shared__ unsigned cur[2056];                     // 8224 B: packed byte cursors
    __shared__ __align__(16) float win[WINCAP + 4];    // 38928 B
    __shared__ float warr[16];
    int s = blockIdx.x % NSEG;
    int p = blockIdx.x / NSEG;
    int t = threadIdx.x;
    int st = seg_starts[s], en = seg_starts[s + 1];
    int n = en - st;
    if (n <= 0) return;
    const unsigned short* pp = pfxg + (size_t)s * PSTRIDE;
    int Fa = Bg[s * 8 + p], Fb = Bg[s * 8 + p + 1];
    int spanc = Fb - Fa;                // entries needed: spanc+1
    int w0 = pp[Fa], w1 = pp[Fb];       // pp[NFB] = n stored
    int wsz = w1 - w0;
    if (wsz <= 0) return;
    const float* ps = part + st + w0;
    bool sliced = (spanc + 1) <= SLICE_E;

    float rv[EPT]; int rr[EPT];
    if (sliced) {
        for (int k = t; k <= spanc; k += BT) slice[k] = pp[Fa + k];
        for (int k = t; k < ((spanc + 4) >> 2); k += BT) cur[k] = 0u;
        __syncthreads();
        // stage: coalesced slice read -> bin-grouped win via byte cursors
        int head = min(wsz, (int)((4 - ((st + w0) & 3)) & 3));
        for (int k = t; k < head; k += BT) {
            float v = ps[k];
            int i = fbin_of(v) - Fa;
            unsigned shf = (i & 3) * 8;
            unsigned old = atomicAdd(&cur[i >> 2], 1u << shf);
            win[(int)slice[i] - w0 + (int)((old >> shf) & 0xFFu)] = v;
        }
        int nv = (wsz - head) >> 2;
        const float4* ps4 = (const float4*)(ps + head);
        for (int j = t; j < nv; j += BT) {
            float4 v4 = ps4[j];
            #pragma unroll
            for (int e = 0; e < 4; ++e) {
                float v = (e == 0) ? v4.x : (e == 1) ? v4.y : (e == 2) ? v4.z : v4.w;
                int i = fbin_of(v) - Fa;
                unsigned shf = (i & 3) * 8;
                unsigned old = atomicAdd(&cur[i >> 2], 1u << shf);
                win[(int)slice[i] - w0 + (int)((old >> shf) & 0xFFu)] = v;
            }
        }
        for (int k = head + nv * 4 + t; k < wsz; k += BT) {
            float v = ps[k];
            int i = fbin_of(v) - Fa;
            unsigned shf = (i & 3) * 8;
            unsigned old = atomicAdd(&cur[i >> 2], 1u << shf);
            win[(int)slice[i] - w0 + (int)((old >> shf) & 0xFFu)] = v;
        }
        if (t < 4) win[wsz + t] = __builtin_inff();
        __syncthreads();
        // rank within fine bin; consecutive ql per lane keeps LDS reads conflict-free
        // (monotone bins: under-read strictly smaller -> cancelled; over-read -> 0)
        #pragma unroll
        for (int e = 0; e < EPT; ++e) {
            int ql = e * BT + t;
            rr[e] = -1;
            if (ql < wsz) {
                float v = win[ql];
                rv[e] = v;
                int i = fbin_of(v) - Fa;
                int ls = (int)slice[i] - w0, le = (int)slice[i + 1] - w0;
                int a = ls & ~3;
                int cnt = a - ls;
                for (int j = a; j < le; j += 4) {
                    float4 qv = *(const float4*)&win[j];
                    cnt += (qv.x < v) + ((qv.x == v) & (j + 0 < ql));
                    cnt += (qv.y < v) + ((qv.y == v) & (j + 1 < ql));
                    cnt += (qv.z < v) + ((qv.z == v) & (j + 2 < ql));
                    cnt += (qv.w < v) + ((qv.w == v) & (j + 3 < ql));
                }
                rr[e] = ls + cnt;
            }
        }
    } else {
        // fallback (span exceeds slice cap — degenerate only): linear stage,
        // whole-window rank (window is bin-aligned).
        for (int k = t; k < wsz; k += BT) win[k] = ps[k];
        if (t < 4) win[wsz + t] = __builtin_inff();
        __syncthreads();
        #pragma unroll
        for (int e = 0; e < EPT; ++e) {
            int ql = e * BT + t;
            rr[e] = -1;
            if (ql < wsz) {
                float v = win[ql];
                rv[e] = v;
                int cnt = 0;
                for (int j = 0; j < wsz; j += 4) {
                    float4 qv = *(const float4*)&win[j];
                    cnt += (qv.x < v) + ((qv.x == v) & (j + 0 < ql));
                    cnt += (qv.y < v) + ((qv.y == v) & (j + 1 < ql));
                    cnt += (qv.z < v) + ((qv.z == v) & (j + 2 < ql));
                    cnt += (qv.w < v) + ((qv.w == v) & (j + 3 < ql));
                }
                rr[e] = cnt;
            }
        }
    }
    __syncthreads();
    // in-place sorted rewrite (rr is a bijection on [0,wsz))
    #pragma unroll
    for (int e = 0; e < EPT; ++e) {
        if (rr[e] >= 0) win[rr[e]] = rv[e];
    }
    __syncthreads();
    // coalesced diff against y
    float acc = 0.f;
    const float* yw = y + st + w0;
    int head2 = min(wsz, (int)((4 - ((st + w0) & 3)) & 3));
    for (int k = t; k < head2; k += BT) acc += fabsf(win[k] - yw[k]);
    int nv2 = (wsz - head2) >> 2;
    const float4* yw4 = (const float4*)(yw + head2);
    for (int j = t; j < nv2; j += BT) {
        float4 yv = yw4[j];
        int k = head2 + j * 4;
        acc += fabsf(win[k + 0] - yv.x);
        acc += fabsf(win[k + 1] - yv.y);
        acc += fabsf(win[k + 2] - yv.z);
        acc += fabsf(win[k + 3] - yv.w);
    }
    for (int k = head2 + nv2 * 4 + t; k < wsz; k += BT) acc += fabsf(win[k] - yw[k]);

    for (int off = 32; off > 0; off >>= 1) acc += __shfl_xor(acc, off, 64);
    if ((t & 63) == 0) warr[t >> 6] = acc;
    __syncthreads();
    if (t == 0) {
        float tot = 0.f;
        #pragma unroll
        for (int j = 0; j < 16; ++j) tot += warr[j];
        if (tot != 0.f) atomicAdd(&segSums[s], tot);
    }
}

// ---- 4. finalize: mean over segments of sum/n * strength ----
__global__ void k_final(const float* __restrict__ segSums, const int* __restrict__ seg_starts,
                        float* __restrict__ out) {
    __shared__ float red[256];
    int t = threadIdx.x;
    float a = 0.f;
    for (int k = t; k < NSEG; k += 256) {
        float n = (float)(seg_starts[k + 1] - seg_starts[k]);
        a += segSums[k] / fmaxf(n, 1.0f);
    }
    red[t] = a;
    __syncthreads();
    for (int off = 128; off > 0; off >>= 1) {
        if (t < off) red[t] += red[t + off];
        __syncthreads();
    }
    if (t == 0) out[0] = red[0] * (1.0f / (float)NSEG) * STRENGTH;
}

extern "C" void kernel_launch(void* const* d_in, const int* in_sizes, int n_in,
                              void* d_out, int out_size, void* d_ws, size_t ws_size,
                              hipStream_t stream) {
    const float* x = (const float*)d_in[0];
    const float* y = (const float*)d_in[1];          // initial_sorted
    const int* seg = (const int*)d_in[2];            // segment_ids (sorted)
    int N = in_sizes[0];

    char* ws = (char*)d_ws;
    float* segSums    = (float*)ws;                          // 200 f32      @0
    int*   seg_starts = (int*)(ws + 800);                    // 201 i32      @800
    unsigned* gcur    = (unsigned*)(ws + 1616);              // 1600 u32     @1616
    int*   Bg         = (int*)(ws + 8016);                   // 1608 i32     @8016
    int*   Bpos      = (int*)(ws + 14448);                   // 1608 i32     @14448
    unsigned short* pfxg = (unsigned short*)(ws + 20880);    // 200*PSTRIDE u16
    float* part       = (float*)(ws + 20880 + (size_t)NSEG * PSTRIDE * 2 + 16);
    unsigned* histp   = (unsigned*)part;                     // alias: consumed by k_hist2
                                                             // before k_part writes part

    int nchunk = (N + PCH - 1) / PCH;

    k_hist1<<<NSEG * QH, BT, 0, stream>>>(x, seg, seg_starts, segSums, gcur, histp, N);
    k_hist2<<<NSEG, BT, 0, stream>>>(histp, pfxg, Bg, Bpos);
    k_part<<<nchunk, 1024, 0, stream>>>(x, seg_starts, Bg, Bpos, gcur, part, N);
    k_seg<<<NSEG * SPLIT, BT, 0, stream>>>(part, y, seg_starts, pfxg, Bg, segSums);
    k_final<<<1, 256, 0, stream>>>(segSums, seg_starts, (float*)d_out);
}

// Round 23
// 89.651 us; speedup vs baseline: 1.1585x; 1.1585x over previous
//
#include <hip/hip_runtime.h>
#include <hip/hip_bf16.h>

#define NSEG 200
#define STRENGTH 1e-3f
#define NFB 16384                   // fine bins per segment
#define FSCALE (16384.0f / 12.0f)
#define BT 1024                     // threads per k_hist/k_seg block
#define SPLIT 5                     // windows (partitions) per segment
#define WINCAP 9728                 // max window slots (n/5 + maxbin + slack)
#define EPT 10                      // max elements per thread
#define PSTRIDE (NFB + 8)           // u16 per segment in global pfx table
#define PCH 8192                    // elements per k_part chunk
#define SLICE_E 8200                // LDS pfx slice capacity (entries)

__device__ __forceinline__ int fbin_of(float v) {
    float t = (v + 6.0f) * FSCALE;
    int b = (int)floorf(t);
    return b < 0 ? 0 : (b > NFB - 1 ? NFB - 1 : b);
}

// ---- 1. per-segment: bounds search + fine hist (packed u16) + prefix -> pfxg; quantile bounds ----
__global__ void __launch_bounds__(BT)
k_hist(const float* __restrict__ x, const int* __restrict__ seg,
       int* __restrict__ seg_starts, float* __restrict__ segSums,
       unsigned* __restrict__ gcur, unsigned short* __restrict__ pfxg,
       int* __restrict__ Bg, int* __restrict__ Bpos, int N) {
    __shared__ unsigned hw[NFB / 2];    // 32 KB: packed u16 counts -> packed u16 prefix
    __shared__ unsigned wsum[16];
    __shared__ int sh2[3];
    int s = blockIdx.x;
    int t = threadIdx.x;
    if (t <= 1) {
        int key = s + t;
        int lo = 0, hi = N;
        while (lo < hi) { int mid = (lo + hi) >> 1; if (seg[mid] < key) lo = mid + 1; else hi = mid; }
        sh2[t] = lo;
    }
    if (t < 8) gcur[s * 8 + t] = 0u;
    if (t == 2) segSums[s] = 0.f;
    for (int k = t; k < NFB / 2; k += BT) hw[k] = 0;
    __syncthreads();
    int st = sh2[0], en = sh2[1];
    if (t == 3) { seg_starts[s] = st; if (s == NSEG - 1) seg_starts[NSEG] = N; }
    int n = en - st;
    const float* xs = x + st;
    if (n > 0) {
        int head = min(n, (int)((4 - (st & 3)) & 3));
        for (int k = t; k < head; k += BT) { int f = fbin_of(xs[k]); atomicAdd(&hw[f >> 1], 1u << ((f & 1) * 16)); }
        int nv = (n - head) >> 2;
        const float4* xs4 = (const float4*)(xs + head);
        for (int j = t; j < nv; j += BT) {
            float4 v = xs4[j];
            int f0 = fbin_of(v.x), f1 = fbin_of(v.y), f2 = fbin_of(v.z), f3 = fbin_of(v.w);
            atomicAdd(&hw[f0 >> 1], 1u << ((f0 & 1) * 16));
            atomicAdd(&hw[f1 >> 1], 1u << ((f1 & 1) * 16));
            atomicAdd(&hw[f2 >> 1], 1u << ((f2 & 1) * 16));
            atomicAdd(&hw[f3 >> 1], 1u << ((f3 & 1) * 16));
        }
        for (int k = head + nv * 4 + t; k < n; k += BT) { int f = fbin_of(xs[k]); atomicAdd(&hw[f >> 1], 1u << ((f & 1) * 16)); }
    }
    __syncthreads();
    // exclusive prefix over 16384 bins: thread owns 8 words (16 bins)
    unsigned wv[8]; unsigned run = 0;
    #pragma unroll
    for (int i = 0; i < 8; ++i) {
        unsigned w = hw[t * 8 + i];
        unsigned c0 = w & 0xffffu, c1 = w >> 16;
        wv[i] = run | ((run + c0) << 16);
        run += c0 + c1;
    }
    unsigned incl = run;
    for (int off = 1; off < 64; off <<= 1) {
        unsigned nv2 = __shfl_up(incl, off, 64);
        if ((t & 63) >= off) incl += nv2;
    }
    if ((t & 63) == 63) wsum[t >> 6] = incl;
    __syncthreads();
    unsigned wb = 0; int myw = t >> 6;
    #pragma unroll
    for (int j = 0; j < 16; ++j) wb += (j < myw) ? wsum[j] : 0u;
    unsigned base = wb + incl - run;
    unsigned bb = base | (base << 16);
    unsigned short* pp = pfxg + (size_t)s * PSTRIDE;
    #pragma unroll
    for (int i = 0; i < 8; ++i) {
        unsigned pw = wv[i] + bb;
        hw[t * 8 + i] = pw;                       // keep packed prefix for quantile search
        ((unsigned*)pp)[t * 8 + i] = pw;          // global u16 prefix table
    }
    if (t == BT - 1) { pp[NFB] = (unsigned short)(base + run); sh2[2] = (int)(base + run); }
    __syncthreads();
    int nsh = sh2[2];
    if (t == 0) { Bg[s * 8 + 0] = 0; Bg[s * 8 + SPLIT] = NFB; Bpos[s * 8 + 0] = 0; Bpos[s * 8 + SPLIT] = nsh; }
    if (t >= 1 && t < SPLIT) {
        int target = (int)(((long)t * nsh) / SPLIT);
        int lo = 0, hi = NFB - 1;
        while (lo < hi) {
            int mid = (lo + hi) >> 1;
            int pv = (int)((hw[(mid + 1) >> 1] >> (((mid + 1) & 1) * 16)) & 0xffffu);
            if (pv > target) hi = mid; else lo = mid + 1;
        }
        Bg[s * 8 + t] = lo;
        Bpos[s * 8 + t] = (int)((hw[lo >> 1] >> ((lo & 1) * 16)) & 0xffffu);
    }
}

// ---- 2. single-pass 5-way partition scatter (block-aggregated, coalesced runs) ----
__global__ void __launch_bounds__(1024)
k_part(const float* __restrict__ x, const int* __restrict__ seg_starts,
       const int* __restrict__ Bg, const int* __restrict__ Bpos,
       unsigned* __restrict__ gcur, float* __restrict__ part, int N) {
    __shared__ int sst[NSEG + 1];
    __shared__ unsigned hh[16][12];
    __shared__ int gb[10];
    __shared__ int sB[8];
    int t = threadIdx.x;
    for (int k = t; k < NSEG + 1; k += 1024) sst[k] = seg_starts[k];
    if (t < 192) ((unsigned*)hh)[t] = 0u;
    __syncthreads();
    int base = blockIdx.x * PCH;
    if (base >= N) return;
    int lo = 0, hi = NSEG - 1;
    while (lo < hi) { int mid = (lo + hi) >> 1; if (base < sst[mid + 1]) hi = mid; else lo = mid + 1; }
    int s0 = lo, bnd = sst[s0 + 1];
    if (t < 4) sB[t] = Bg[s0 * 8 + 1 + t];
    else if (t < 8) sB[t] = (s0 + 1 < NSEG) ? Bg[(s0 + 1) * 8 + 1 + (t - 4)] : 0x7fffffff;
    __syncthreads();
    int grp = t >> 6;
    float vv[8]; unsigned pk[8];
    const float4* x4 = (const float4*)(x + base);
    #pragma unroll
    for (int it = 0; it < 2; ++it) {
        int j = it * 1024 + t;
        int gi = base + j * 4;
        float4 v4 = (gi + 3 < N) ? x4[j] : make_float4(0.f, 0.f, 0.f, 0.f);
        #pragma unroll
        for (int e = 0; e < 4; ++e) {
            int i = it * 4 + e;
            float v = (e == 0) ? v4.x : (e == 1) ? v4.y : (e == 2) ? v4.z : v4.w;
            vv[i] = v;
            int g = gi + e;
            if (g < N) {
                int off = (g >= bnd) ? 4 : 0;
                int f = fbin_of(v);
                int p = (f >= sB[off]) + (f >= sB[off + 1]) + (f >= sB[off + 2]) + (f >= sB[off + 3]);
                int sp = (off >> 2) * 5 + p;
                unsigned lr = atomicAdd(&hh[grp][sp], 1u);
                pk[i] = ((unsigned)sp << 10) | lr;
            } else pk[i] = 0xffffffffu;
        }
    }
    __syncthreads();
    if (t < 10) {
        unsigned run = 0;
        #pragma unroll
        for (int g = 0; g < 16; ++g) { unsigned c = hh[g][t]; hh[g][t] = run; run += c; }
        int s = s0 + (t >= 5);
        int p = (t >= 5) ? t - 5 : t;
        int rsv = 0;
        if (run > 0 && s < NSEG) rsv = (int)atomicAdd(&gcur[s * 8 + p], run);
        gb[t] = (s < NSEG) ? (sst[s] + Bpos[s * 8 + p] + rsv) : 0;
    }
    __syncthreads();
    #pragma unroll
    for (int i = 0; i < 8; ++i) {
        if (pk[i] == 0xffffffffu) continue;
        int sp = (int)(pk[i] >> 10);
        int lr = (int)(pk[i] & 1023u);
        part[gb[sp] + (int)hh[grp][sp] + lr] = vv[i];
    }
}

// ---- 3. per-(segment,window): slice-pfx stage -> rank -> in-place sort -> coalesced diff ----
// s = bid % NSEG keeps all 5 blocks of a segment on one XCD (NSEG % 8 == 0).
__global__ void __launch_bounds__(BT)
k_seg(const float* __restrict__ part, const float* __restrict__ y,
      const int* __restrict__ seg_starts, const unsigned short* __restrict__ pfxg,
      const int* __restrict__ Bg, float* __restrict__ segSums) {
    __shared__ unsigned short slice[SLICE_E];          // 16400 B: pfx[Fa..Fb]
    __shared__ unsigned cur[2056];                     // 8224 B: packed byte cursors
    __shared__ __align__(16) float win[WINCAP + 4];    // 38928 B
    __shared__ float warr[16];
    int s = blockIdx.x % NSEG;
    int p = blockIdx.x / NSEG;
    int t = threadIdx.x;
    int st = seg_starts[s], en = seg_starts[s + 1];
    int n = en - st;
    if (n <= 0) return;
    const unsigned short* pp = pfxg + (size_t)s * PSTRIDE;
    int Fa = Bg[s * 8 + p], Fb = Bg[s * 8 + p + 1];
    int spanc = Fb - Fa;                // entries needed: spanc+1
    int w0 = pp[Fa], w1 = pp[Fb];       // pp[NFB] = n stored
    int wsz = w1 - w0;
    if (wsz <= 0) return;
    const float* ps = part + st + w0;
    bool sliced = (spanc + 1) <= SLICE_E;

    float rv[EPT]; int rr[EPT];
    if (sliced) {
        for (int k = t; k <= spanc; k += BT) slice[k] = pp[Fa + k];
        for (int k = t; k < ((spanc + 4) >> 2); k += BT) cur[k] = 0u;
        __syncthreads();
        // stage: coalesced slice read -> bin-grouped win via byte cursors
        int head = min(wsz, (int)((4 - ((st + w0) & 3)) & 3));
        for (int k = t; k < head; k += BT) {
            float v = ps[k];
            int i = fbin_of(v) - Fa;
            unsigned shf = (i & 3) * 8;
            unsigned old = atomicAdd(&cur[i >> 2], 1u << shf);
            win[(int)slice[i] - w0 + (int)((old >> shf) & 0xFFu)] = v;
        }
        int nv = (wsz - head) >> 2;
        const float4* ps4 = (const float4*)(ps + head);
        for (int j = t; j < nv; j += BT) {
            float4 v4 = ps4[j];
            #pragma unroll
            for (int e = 0; e < 4; ++e) {
                float v = (e == 0) ? v4.x : (e == 1) ? v4.y : (e == 2) ? v4.z : v4.w;
                int i = fbin_of(v) - Fa;
                unsigned shf = (i & 3) * 8;
                unsigned old = atomicAdd(&cur[i >> 2], 1u << shf);
                win[(int)slice[i] - w0 + (int)((old >> shf) & 0xFFu)] = v;
            }
        }
        for (int k = head + nv * 4 + t; k < wsz; k += BT) {
            float v = ps[k];
            int i = fbin_of(v) - Fa;
            unsigned shf = (i & 3) * 8;
            unsigned old = atomicAdd(&cur[i >> 2], 1u << shf);
            win[(int)slice[i] - w0 + (int)((old >> shf) & 0xFFu)] = v;
        }
        if (t < 4) win[wsz + t] = __builtin_inff();
        __syncthreads();
        // rank within fine bin; consecutive ql per lane keeps LDS reads conflict-free
        // (monotone bins: under-read strictly smaller -> cancelled; over-read -> 0)
        #pragma unroll
        for (int e = 0; e < EPT; ++e) {
            int ql = e * BT + t;
            rr[e] = -1;
            if (ql < wsz) {
                float v = win[ql];
                rv[e] = v;
                int i = fbin_of(v) - Fa;
                int ls = (int)slice[i] - w0, le = (int)slice[i + 1] - w0;
                int a = ls & ~3;
                int cnt = a - ls;
                for (int j = a; j < le; j += 4) {
                    float4 qv = *(const float4*)&win[j];
                    cnt += (qv.x < v) + ((qv.x == v) & (j + 0 < ql));
                    cnt += (qv.y < v) + ((qv.y == v) & (j + 1 < ql));
                    cnt += (qv.z < v) + ((qv.z == v) & (j + 2 < ql));
                    cnt += (qv.w < v) + ((qv.w == v) & (j + 3 < ql));
                }
                rr[e] = ls + cnt;
            }
        }
    } else {
        // fallback (span exceeds slice cap — degenerate only): linear stage,
        // whole-window rank (window is bin-aligned).
        for (int k = t; k < wsz; k += BT) win[k] = ps[k];
        if (t < 4) win[wsz + t] = __builtin_inff();
        __syncthreads();
        #pragma unroll
        for (int e = 0; e < EPT; ++e) {
            int ql = e * BT + t;
            rr[e] = -1;
            if (ql < wsz) {
                float v = win[ql];
                rv[e] = v;
                int cnt = 0;
                for (int j = 0; j < wsz; j += 4) {
                    float4 qv = *(const float4*)&win[j];
                    cnt += (qv.x < v) + ((qv.x == v) & (j + 0 < ql));
                    cnt += (qv.y < v) + ((qv.y == v) & (j + 1 < ql));
                    cnt += (qv.z < v) + ((qv.z == v) & (j + 2 < ql));
                    cnt += (qv.w < v) + ((qv.w == v) & (j + 3 < ql));
                }
                rr[e] = cnt;
            }
        }
    }
    __syncthreads();
    // in-place sorted rewrite (rr is a bijection on [0,wsz))
    #pragma unroll
    for (int e = 0; e < EPT; ++e) {
        if (rr[e] >= 0) win[rr[e]] = rv[e];
    }
    __syncthreads();
    // coalesced diff against y
    float acc = 0.f;
    const float* yw = y + st + w0;
    int head2 = min(wsz, (int)((4 - ((st + w0) & 3)) & 3));
    for (int k = t; k < head2; k += BT) acc += fabsf(win[k] - yw[k]);
    int nv2 = (wsz - head2) >> 2;
    const float4* yw4 = (const float4*)(yw + head2);
    for (int j = t; j < nv2; j += BT) {
        float4 yv = yw4[j];
        int k = head2 + j * 4;
        acc += fabsf(win[k + 0] - yv.x);
        acc += fabsf(win[k + 1] - yv.y);
        acc += fabsf(win[k + 2] - yv.z);
        acc += fabsf(win[k + 3] - yv.w);
    }
    for (int k = head2 + nv2 * 4 + t; k < wsz; k += BT) acc += fabsf(win[k] - yw[k]);

    for (int off = 32; off > 0; off >>= 1) acc += __shfl_xor(acc, off, 64);
    if ((t & 63) == 0) warr[t >> 6] = acc;
    __syncthreads();
    if (t == 0) {
        float tot = 0.f;
        #pragma unroll
        for (int j = 0; j < 16; ++j) tot += warr[j];
        if (tot != 0.f) atomicAdd(&segSums[s], tot);
    }
}

// ---- 4. finalize: mean over segments of sum/n * strength ----
__global__ void k_final(const float* __restrict__ segSums, const int* __restrict__ seg_starts,
                        float* __restrict__ out) {
    __shared__ float red[256];
    int t = threadIdx.x;
    float a = 0.f;
    for (int k = t; k < NSEG; k += 256) {
        float n = (float)(seg_starts[k + 1] - seg_starts[k]);
        a += segSums[k] / fmaxf(n, 1.0f);
    }
    red[t] = a;
    __syncthreads();
    for (int off = 128; off > 0; off >>= 1) {
        if (t < off) red[t] += red[t + off];
        __syncthreads();
    }
    if (t == 0) out[0] = red[0] * (1.0f / (float)NSEG) * STRENGTH;
}

extern "C" void kernel_launch(void* const* d_in, const int* in_sizes, int n_in,
                              void* d_out, int out_size, void* d_ws, size_t ws_size,
                              hipStream_t stream) {
    const float* x = (const float*)d_in[0];
    const float* y = (const float*)d_in[1];          // initial_sorted
    const int* seg = (const int*)d_in[2];            // segment_ids (sorted)
    int N = in_sizes[0];

    char* ws = (char*)d_ws;
    float* segSums    = (float*)ws;                          // 200 f32      @0
    int*   seg_starts = (int*)(ws + 800);                    // 201 i32      @800
    unsigned* gcur    = (unsigned*)(ws + 1616);              // 1600 u32     @1616
    int*   Bg         = (int*)(ws + 8016);                   // 1608 i32     @8016
    int*   Bpos       = (int*)(ws + 14448);                  // 1608 i32     @14448
    unsigned short* pfxg = (unsigned short*)(ws + 20880);    // 200*PSTRIDE u16
    float* part       = (float*)(ws + 20880 + (size_t)NSEG * PSTRIDE * 2 + 16);

    int nchunk = (N + PCH - 1) / PCH;

    k_hist<<<NSEG, BT, 0, stream>>>(x, seg, seg_starts, segSums, gcur, pfxg, Bg, Bpos, N);
    k_part<<<nchunk, 1024, 0, stream>>>(x, seg_starts, Bg, Bpos, gcur, part, N);
    k_seg<<<NSEG * SPLIT, BT, 0, stream>>>(part, y, seg_starts, pfxg, Bg, segSums);
    k_final<<<1, 256, 0, stream>>>(segSums, seg_starts, (float*)d_out);
}